// Round 3
// baseline (25856.317 us; speedup 1.0000x reference)
//
#include <hip/hip_runtime.h>
#include <math.h>

#define Bz 32
#define Tz 20
#define TMz 19
#define Vz 10000
#define INFLAT 262144   // P*D
#define RELSZ 16384
#define NBLK 256

// workspace float offsets
#define WS_PH     0
#define WS_PC     4194304
#define WS_ATT1   0              // reuses ph/pc region after k_reduce3
#define WS_EXPE   8388608
#define WS_ZPART  8421376
#define WS_AWFP   8421632        // 8*32*256 = 65536
#define WS_GWH    8487168        // 5*6*32*256 = 245760
#define WS_HST    8732928
#define WS_CST    8741120
#define WS_CSTB   8749312
#define WS_INTS   8757504        // ordp(32) slp(32) bar(8)
#define WS_PCHC   8757632        // 128*32*256 = 1048576 -> end 9806208 (~39.2MB)

__device__ __forceinline__ float sigm(float x) { return 1.0f / (1.0f + expf(-x)); }

__device__ __forceinline__ void gl_lds16(const float* g, float* l) {
    __builtin_amdgcn_global_load_lds(
        (const __attribute__((address_space(1))) unsigned int*)g,
        (__attribute__((address_space(3))) unsigned int*)l,
        16, 0, 0);
}

// software grid barrier: bar[0]=arrive counter, bar[1]=generation
__device__ __forceinline__ void gbar(int* bar) {
    __syncthreads();
    if (threadIdx.x == 0) {
        __threadfence();
        int gen = __hip_atomic_load(&bar[1], __ATOMIC_RELAXED, __HIP_MEMORY_SCOPE_AGENT);
        int prev = __hip_atomic_fetch_add(&bar[0], 1, __ATOMIC_ACQ_REL, __HIP_MEMORY_SCOPE_AGENT);
        if (prev == NBLK - 1) {
            __hip_atomic_store(&bar[0], 0, __ATOMIC_RELAXED, __HIP_MEMORY_SCOPE_AGENT);
            __hip_atomic_fetch_add(&bar[1], 1, __ATOMIC_ACQ_REL, __HIP_MEMORY_SCOPE_AGENT);
        } else {
            int g2;
            do {
                __builtin_amdgcn_s_sleep(2);
                g2 = __hip_atomic_load(&bar[1], __ATOMIC_ACQUIRE, __HIP_MEMORY_SCOPE_AGENT);
            } while (g2 == gen);
        }
        __threadfence();
    }
    __syncthreads();
}

// ---------------- sort + barrier init ----------------
__global__ void k_sort(const int* __restrict__ lens, float* __restrict__ out_order,
                       int* __restrict__ ord, int* __restrict__ sentlen, int* __restrict__ bar) {
    if (threadIdx.x == 0 && blockIdx.x == 0) {
        bar[0] = 0; bar[1] = 0;
        int l[Bz]; bool used[Bz];
        for (int b = 0; b < Bz; ++b) { l[b] = lens[b]; used[b] = false; }
        for (int i = 0; i < Bz; ++i) {
            int best = -1;
            for (int j = 0; j < Bz; ++j)
                if (!used[j] && (best < 0 || l[j] > l[best])) best = j;
            used[best] = true;
            ord[i] = best;
            sentlen[i] = l[best] - 1;
            out_order[i] = (float)best;
        }
    }
}

// ---------------- h0,c0: flat(32,262144) @ W_ih / W_ic ----------------
__global__ __launch_bounds__(256) void k_gemv2(const float* __restrict__ X, const int* __restrict__ ord,
                                               const float* __restrict__ W1, const float* __restrict__ W2,
                                               float* __restrict__ p1, float* __restrict__ p2) {
    __shared__ __align__(16) float wlds[8192];      // 2 slots x (8 rows x 256 x 2 mats)
    __shared__ __align__(16) float xsT[256 * 36];   // [k 0..255][b 0..31] pad 36
    __shared__ int ords[32];
    int tid = threadIdx.x;
    int wv = tid >> 6, ln = tid & 63;
    size_t k0 = (size_t)blockIdx.x * 512;

    if (tid < 32) ords[tid] = ord[tid];
    __syncthreads();

    auto stage_xs = [&](int hh) {
        for (int idx = tid; idx < 2048; idx += 256) {
            int b = idx >> 6, kq = idx & 63;
            float4 v = *(const float4*)&X[(size_t)ords[b] * INFLAT + k0 + (size_t)hh * 256 + kq * 4];
            xsT[(kq * 4 + 0) * 36 + b] = v.x;
            xsT[(kq * 4 + 1) * 36 + b] = v.y;
            xsT[(kq * 4 + 2) * 36 + b] = v.z;
            xsT[(kq * 4 + 3) * 36 + b] = v.w;
        }
    };
    auto issue = [&](int n) {
        int slot = n & 1;
        size_t krow = k0 + (size_t)n * 8 + wv * 2;
        const float* g1 = W1 + krow * 256 + ln * 4;
        const float* g2 = W2 + krow * 256 + ln * 4;
        float* l1 = &wlds[slot * 4096 + (wv * 2) * 256 + ln * 4];
        float* l2 = &wlds[slot * 4096 + 2048 + (wv * 2) * 256 + ln * 4];
        gl_lds16(g1, l1);
        gl_lds16(g2, l2);
        gl_lds16(g1 + 256, l1 + 256);
        gl_lds16(g2 + 256, l2 + 256);
    };

    float ah[32], ac[32];
#pragma unroll
    for (int b = 0; b < 32; ++b) { ah[b] = 0.f; ac[b] = 0.f; }

    stage_xs(0);
    issue(0);

#pragma unroll 1
    for (int c = 0; c < 64; ++c) {
        if (c == 32) stage_xs(1);
        if (c + 1 < 64) {
            issue(c + 1);
            asm volatile("s_waitcnt vmcnt(4)" ::: "memory");
        } else {
            asm volatile("s_waitcnt vmcnt(0)" ::: "memory");
        }
        __syncthreads();
        int slot = c & 1;
        int xb0 = (c & 31) * 8;
#pragma unroll
        for (int kk = 0; kk < 8; ++kk) {
            float w1 = wlds[slot * 4096 + kk * 256 + tid];
            float w2 = wlds[slot * 4096 + 2048 + kk * 256 + tid];
            const float4* xr = (const float4*)&xsT[(xb0 + kk) * 36];
#pragma unroll
            for (int bq = 0; bq < 8; ++bq) {
                float4 x4 = xr[bq];
                ah[bq * 4 + 0] += x4.x * w1; ac[bq * 4 + 0] += x4.x * w2;
                ah[bq * 4 + 1] += x4.y * w1; ac[bq * 4 + 1] += x4.y * w2;
                ah[bq * 4 + 2] += x4.z * w1; ac[bq * 4 + 2] += x4.z * w2;
                ah[bq * 4 + 3] += x4.w * w1; ac[bq * 4 + 3] += x4.w * w2;
            }
        }
        __syncthreads();
    }
#pragma unroll
    for (int b = 0; b < 32; ++b) {
        size_t o = ((size_t)blockIdx.x * 32 + b) * 256 + tid;
        p1[o] = ah[b];
        p2[o] = ac[b];
    }
}

// ---------------- C0: rel(32,16384) @ W_iC, split-K ----------------
__global__ __launch_bounds__(256) void k_gemvC(const float* __restrict__ R, const int* __restrict__ ord,
                                               const float* __restrict__ W, float* __restrict__ p) {
    __shared__ float xs[32 * 128];
    __shared__ int ords[32];
    int tid = threadIdx.x, bx = blockIdx.x;
    if (tid < 32) ords[tid] = ord[tid];
    __syncthreads();
    int k0 = bx * 128;
    for (int idx = tid; idx < 32 * 128; idx += 256) {
        int b = idx >> 7, kk = idx & 127;
        xs[idx] = R[(size_t)ords[b] * RELSZ + k0 + kk];
    }
    __syncthreads();
    float acc[32];
#pragma unroll
    for (int b = 0; b < 32; ++b) acc[b] = 0.f;
    for (int kk = 0; kk < 128; ++kk) {
        float w = W[(size_t)(k0 + kk) * 256 + tid];
#pragma unroll
        for (int b = 0; b < 32; ++b) acc[b] += xs[b * 128 + kk] * w;
    }
#pragma unroll
    for (int b = 0; b < 32; ++b) p[((size_t)bx * 32 + b) * 256 + tid] = acc[b];
}

// ---------------- combined split-K reduces: h0, c0, C0 ----------------
__global__ __launch_bounds__(256) void k_reduce3(const float* __restrict__ ph, const float* __restrict__ pc,
                                                 const float* __restrict__ pC,
                                                 const float* __restrict__ b_ih, const float* __restrict__ b_ic,
                                                 const float* __restrict__ b_iC,
                                                 float* __restrict__ hst, float* __restrict__ cst,
                                                 float* __restrict__ Cst) {
    int which = blockIdx.x >> 5, b = blockIdx.x & 31, j = threadIdx.x;
    if (which == 0) {
        float s0 = b_ih[j], s1 = 0.f, s2 = 0.f, s3 = 0.f;
        for (int c = 0; c < 512; c += 4) {
            s0 += ph[((size_t)((c + 0) * 32 + b)) * 256 + j];
            s1 += ph[((size_t)((c + 1) * 32 + b)) * 256 + j];
            s2 += ph[((size_t)((c + 2) * 32 + b)) * 256 + j];
            s3 += ph[((size_t)((c + 3) * 32 + b)) * 256 + j];
        }
        hst[b * 256 + j] = s0 + s1 + s2 + s3;
    } else if (which == 1) {
        float s0 = b_ic[j], s1 = 0.f, s2 = 0.f, s3 = 0.f;
        for (int c = 0; c < 512; c += 4) {
            s0 += pc[((size_t)((c + 0) * 32 + b)) * 256 + j];
            s1 += pc[((size_t)((c + 1) * 32 + b)) * 256 + j];
            s2 += pc[((size_t)((c + 2) * 32 + b)) * 256 + j];
            s3 += pc[((size_t)((c + 3) * 32 + b)) * 256 + j];
        }
        cst[b * 256 + j] = s0 + s1 + s2 + s3;
    } else {
        float s0 = b_iC[j], s1 = 0.f, s2 = 0.f, s3 = 0.f;
        for (int c = 0; c < 128; c += 4) {
            s0 += pC[((size_t)((c + 0) * 32 + b)) * 256 + j];
            s1 += pC[((size_t)((c + 1) * 32 + b)) * 256 + j];
            s2 += pC[((size_t)((c + 2) * 32 + b)) * 256 + j];
            s3 += pC[((size_t)((c + 3) * 32 + b)) * 256 + j];
        }
        Cst[b * 256 + j] = s0 + s1 + s2 + s3;
    }
}

// ---------------- att1 = info_sorted @ W_enc + b_enc ----------------
__global__ __launch_bounds__(256) void k_att1(const float* __restrict__ info, const int* __restrict__ ord,
                                              const float* __restrict__ W, const float* __restrict__ bias,
                                              float* __restrict__ att1) {
    __shared__ __align__(16) float xsT[256 * 36];   // [k][row] pad 36
    int tid = threadIdx.x;
    int r0 = blockIdx.x * 32;
    int b = r0 >> 10, p0 = r0 & 1023;
    const float* src = info + (size_t)ord[b] * INFLAT + (size_t)p0 * 256;
    for (int idx = tid; idx < 2048; idx += 256) {
        int r = idx >> 6, kq = idx & 63;
        float4 v = *(const float4*)&src[r * 256 + kq * 4];
        xsT[(kq * 4 + 0) * 36 + r] = v.x;
        xsT[(kq * 4 + 1) * 36 + r] = v.y;
        xsT[(kq * 4 + 2) * 36 + r] = v.z;
        xsT[(kq * 4 + 3) * 36 + r] = v.w;
    }
    __syncthreads();
    float acc[32];
#pragma unroll
    for (int r = 0; r < 32; ++r) acc[r] = 0.f;
    for (int k = 0; k < 256; ++k) {
        float w = W[k * 256 + tid];
        const float4* xr = (const float4*)&xsT[k * 36];
#pragma unroll
        for (int rq = 0; rq < 8; ++rq) {
            float4 x4 = xr[rq];
            acc[rq * 4 + 0] += x4.x * w;
            acc[rq * 4 + 1] += x4.y * w;
            acc[rq * 4 + 2] += x4.z * w;
            acc[rq * 4 + 3] += x4.w * w;
        }
    }
    float bj = bias[tid];
#pragma unroll
    for (int r = 0; r < 32; ++r) att1[((size_t)(r0 + r)) * 256 + tid] = acc[r] + bj;
}

// ---------------- fused steps kernel (software grid barrier) ----------------
struct KArgs {
    const float *info, *emb, *W_dec, *b_dec, *W_full, *b_full;
    const float *W_i, *W_f, *W_o, *W_g1, *W_g2;
    const float *b_i, *b_f, *b_o, *b_g1, *b_g2;
    const float *W_mlp, *b_mlp, *W_fc, *b_fc;
    const int *caps;
    float *att1, *expe, *zpart, *awfp, *gwh, *hst, *cst, *Cst;
    const int *ord, *slp;
    int *bar;
    float *out_pred, *out_alpha;
};

// LDS map (floats): [0..8191] h copy (phase A) / [0..255] awfs + [256..767] cc (phase D)
// [8192..8447] at2, [8448..8575] local expe, [8576..8579] zs, [8704..12799] xb
__device__ void pred_task(const KArgs& a, const float* sm, int tile, int tm1) {
    int tid = threadIdx.x;
    int col = tile * 64 + (tid & 63), bg = tid >> 6;
    if (col >= Vz) return;
    float acc[8] = {0.f, 0.f, 0.f, 0.f, 0.f, 0.f, 0.f, 0.f};
    for (int jq = 0; jq < 64; ++jq) {
        float w0 = a.W_fc[(size_t)(jq * 4 + 0) * Vz + col];
        float w1 = a.W_fc[(size_t)(jq * 4 + 1) * Vz + col];
        float w2 = a.W_fc[(size_t)(jq * 4 + 2) * Vz + col];
        float w3 = a.W_fc[(size_t)(jq * 4 + 3) * Vz + col];
#pragma unroll
        for (int bi = 0; bi < 8; ++bi) {
            float4 h4 = *(const float4*)&sm[(bg * 8 + bi) * 256 + jq * 4];
            acc[bi] += h4.x * w0 + h4.y * w1 + h4.z * w2 + h4.w * w3;
        }
    }
    float bv = a.b_fc[col];
#pragma unroll
    for (int bi = 0; bi < 8; ++bi) {
        int b = bg * 8 + bi;
        float r = (a.slp[b] > tm1) ? (acc[bi] + bv) : 0.f;
        a.out_pred[((size_t)b * TMz + tm1) * Vz + col] = r;
    }
}

__device__ void gwh_task(const KArgs& a, float* sm, int tk, int t) {
    int tid = threadIdx.x;
    int g = tk / 24, r = tk % 24, ct = r / 6, ks = r % 6;
    const float* Wg = (g == 0) ? a.W_i : (g == 1) ? a.W_f : (g == 2) ? a.W_o : (g == 3) ? a.W_g1 : a.W_g2;
    int col = ct * 64 + (tid & 63), bg = tid >> 6;
    float* xb = sm + 8704;
    int wbase, hoff = 0;
    if (ks < 4) {
        wbase = ks * 128;
        for (int idx = tid; idx < 1024; idx += 256) {
            int b = idx >> 5, kq = idx & 31;
            int cap = a.caps[a.ord[b] * Tz + t];
            float4 v = *(const float4*)&a.emb[(size_t)cap * 512 + ks * 128 + kq * 4];
            *(float4*)&xb[b * 128 + kq * 4] = v;
        }
        __syncthreads();
    } else {
        wbase = 768 + (ks - 4) * 128;
        hoff = (ks - 4) * 128;
    }
    float acc[8] = {0.f, 0.f, 0.f, 0.f, 0.f, 0.f, 0.f, 0.f};
    for (int kq = 0; kq < 32; ++kq) {
        float w0 = Wg[(size_t)(wbase + kq * 4 + 0) * 256 + col];
        float w1 = Wg[(size_t)(wbase + kq * 4 + 1) * 256 + col];
        float w2 = Wg[(size_t)(wbase + kq * 4 + 2) * 256 + col];
        float w3 = Wg[(size_t)(wbase + kq * 4 + 3) * 256 + col];
#pragma unroll
        for (int bi = 0; bi < 8; ++bi) {
            int b = bg * 8 + bi;
            const float* xr = (ks < 4) ? &xb[b * 128] : &sm[b * 256 + hoff];
            float4 x4 = *(const float4*)&xr[kq * 4];
            acc[bi] += x4.x * w0 + x4.y * w1 + x4.z * w2 + x4.w * w3;
        }
    }
#pragma unroll
    for (int bi = 0; bi < 8; ++bi)
        a.gwh[((size_t)((g * 6 + ks) * 32 + bg * 8 + bi)) * 256 + col] = acc[bi];
}

__global__ __launch_bounds__(256) void k_steps(KArgs a) {
    __shared__ __align__(16) float sm[12800];
    int bid = blockIdx.x, tid = threadIdx.x;

    for (int t = 0; t < TMz; ++t) {
        // ---------- Phase A ----------
        for (int i = tid; i < 2048; i += 256) ((float4*)sm)[i] = ((const float4*)a.hst)[i];
        __syncthreads();
        int b = bid >> 3, pc = bid & 7;
        int ordb = a.ord[b];
        {
            // at2 (redundant per pc-block)
            float v = a.b_dec[tid];
            const float* hb = sm + b * 256;
            for (int k = 0; k < 256; k += 4) {
                float4 h4 = *(const float4*)&hb[k];
                v += h4.x * a.W_dec[(k + 0) * 256 + tid] + h4.y * a.W_dec[(k + 1) * 256 + tid]
                   + h4.z * a.W_dec[(k + 2) * 256 + tid] + h4.w * a.W_dec[(k + 3) * 256 + tid];
            }
            sm[8192 + tid] = v;
        }
        __syncthreads();
        {
            int wv = tid >> 6, ln = tid & 63;
            float4 wf4 = *(const float4*)&a.W_full[ln * 4];
            float4 a24 = *(const float4*)&sm[8192 + ln * 4];
            float bf = a.b_full[0];
            float zac = 0.f;
            for (int i = 0; i < 32; ++i) {
                int p = pc * 128 + wv * 32 + i;
                float4 r4 = *(const float4*)&a.att1[((size_t)(b * 1024 + p)) * 256 + ln * 4];
                float s = fmaxf(r4.x + a24.x, 0.f) * wf4.x + fmaxf(r4.y + a24.y, 0.f) * wf4.y
                        + fmaxf(r4.z + a24.z, 0.f) * wf4.z + fmaxf(r4.w + a24.w, 0.f) * wf4.w;
                s += __shfl_down(s, 32); s += __shfl_down(s, 16); s += __shfl_down(s, 8);
                s += __shfl_down(s, 4);  s += __shfl_down(s, 2);  s += __shfl_down(s, 1);
                if (ln == 0) {
                    float ex = expf(s + bf);
                    a.expe[b * 1024 + p] = ex;
                    sm[8448 + wv * 32 + i] = ex;
                    zac += ex;
                }
            }
            if (ln == 0) sm[8576 + wv] = zac;
        }
        __syncthreads();
        if (tid == 0) a.zpart[b * 8 + pc] = sm[8576] + sm[8577] + sm[8578] + sm[8579];
        {
            // awf partial over this block's 128 p-rows (unnormalized)
            const float* ib = a.info + (size_t)ordb * INFLAT + (size_t)(pc * 128) * 256;
            float q0 = 0.f, q1 = 0.f, q2 = 0.f, q3 = 0.f;
            for (int i = 0; i < 128; i += 4) {
                q0 += sm[8448 + i + 0] * ib[(size_t)(i + 0) * 256 + tid];
                q1 += sm[8448 + i + 1] * ib[(size_t)(i + 1) * 256 + tid];
                q2 += sm[8448 + i + 2] * ib[(size_t)(i + 2) * 256 + tid];
                q3 += sm[8448 + i + 3] * ib[(size_t)(i + 3) * 256 + tid];
            }
            a.awfp[((size_t)(b * 8 + pc)) * 256 + tid] = (q0 + q1) + (q2 + q3);
        }
        if (t > 0 && bid < 157) pred_task(a, sm, bid, t - 1);
        if (bid >= 136) gwh_task(a, sm, bid - 136, t);
        gbar(a.bar);

        // ---------- Phase D ----------
        if (bid < 32) {
            int bb = bid, j = tid;
            float Z = 0.f;
#pragma unroll
            for (int c = 0; c < 8; ++c) Z += a.zpart[bb * 8 + c];
            float invZ = 1.0f / Z;
            float aw = 0.f;
#pragma unroll
            for (int c = 0; c < 8; ++c) aw += a.awfp[((size_t)(bb * 8 + c)) * 256 + j];
            sm[j] = aw * invZ;   // awfs
            float am = (a.slp[bb] > t) ? invZ : 0.f;
            const float* eb = a.expe + bb * 1024;
            float* oal = a.out_alpha + ((size_t)bb * TMz + t) * 1024;
            for (int p = tid; p < 1024; p += 256) oal[p] = eb[p] * am;
            __syncthreads();

            float gs[5];
#pragma unroll
            for (int g = 0; g < 5; ++g) {
                const float* Wg = (g == 0) ? a.W_i : (g == 1) ? a.W_f : (g == 2) ? a.W_o : (g == 3) ? a.W_g1 : a.W_g2;
                const float* bg = (g == 0) ? a.b_i : (g == 1) ? a.b_f : (g == 2) ? a.b_o : (g == 3) ? a.b_g1 : a.b_g2;
                float s = bg[j];
#pragma unroll
                for (int ks = 0; ks < 6; ++ks) s += a.gwh[((size_t)((g * 6 + ks) * 32 + bb)) * 256 + j];
                float s0 = 0.f, s1 = 0.f, s2 = 0.f, s3 = 0.f;
                for (int kq = 0; kq < 64; ++kq) {
                    float4 x4 = *(const float4*)&sm[kq * 4];
                    s0 += x4.x * Wg[(size_t)(512 + kq * 4 + 0) * 256 + j];
                    s1 += x4.y * Wg[(size_t)(512 + kq * 4 + 1) * 256 + j];
                    s2 += x4.z * Wg[(size_t)(512 + kq * 4 + 2) * 256 + j];
                    s3 += x4.w * Wg[(size_t)(512 + kq * 4 + 3) * 256 + j];
                }
                gs[g] = s + (s0 + s1) + (s2 + s3);
            }
            float iv = sigm(gs[0]), fv = sigm(gs[1]), ov = sigm(gs[2]);
            float g1 = tanhf(gs[3]), g2 = tanhf(gs[4]);
            float nc = fv * a.cst[bb * 256 + j] + iv * g1;
            float nC = fv * a.Cst[bb * 256 + j] + iv * g2;
            a.cst[bb * 256 + j] = nc;
            a.Cst[bb * 256 + j] = nC;
            sm[256 + j] = nc;
            sm[512 + j] = nC;
            __syncthreads();
            float m0 = a.b_mlp[j], m1 = 0.f, m2 = 0.f, m3 = 0.f;
            for (int kq = 0; kq < 128; ++kq) {
                float4 c4 = *(const float4*)&sm[256 + kq * 4];
                m0 += c4.x * a.W_mlp[(size_t)(kq * 4 + 0) * 256 + j];
                m1 += c4.y * a.W_mlp[(size_t)(kq * 4 + 1) * 256 + j];
                m2 += c4.z * a.W_mlp[(size_t)(kq * 4 + 2) * 256 + j];
                m3 += c4.w * a.W_mlp[(size_t)(kq * 4 + 3) * 256 + j];
            }
            a.hst[bb * 256 + j] = ov * tanhf((m0 + m1) + (m2 + m3));
        }
        gbar(a.bar);
    }

    // epilogue: pred for t = 18
    for (int i = tid; i < 2048; i += 256) ((float4*)sm)[i] = ((const float4*)a.hst)[i];
    __syncthreads();
    if (bid < 157) pred_task(a, sm, bid, TMz - 1);
}

extern "C" void kernel_launch(void* const* d_in, const int* in_sizes, int n_in,
                              void* d_out, int out_size, void* d_ws, size_t ws_size,
                              hipStream_t stream) {
    const float* info  = (const float*)d_in[0];
    const float* rel   = (const float*)d_in[1];
    const int*   caps  = (const int*)d_in[2];
    const int*   lens  = (const int*)d_in[3];
    const float* emb   = (const float*)d_in[4];
    const float* W_enc = (const float*)d_in[5];
    const float* b_enc = (const float*)d_in[6];
    const float* W_dec = (const float*)d_in[7];
    const float* b_dec = (const float*)d_in[8];
    const float* W_full= (const float*)d_in[9];
    const float* b_full= (const float*)d_in[10];
    const float* W_i   = (const float*)d_in[11];
    const float* b_i   = (const float*)d_in[12];
    const float* W_f   = (const float*)d_in[13];
    const float* b_f   = (const float*)d_in[14];
    const float* W_o   = (const float*)d_in[15];
    const float* b_o   = (const float*)d_in[16];
    const float* W_g1  = (const float*)d_in[17];
    const float* b_g1  = (const float*)d_in[18];
    const float* W_g2  = (const float*)d_in[19];
    const float* b_g2  = (const float*)d_in[20];
    const float* W_mlp = (const float*)d_in[21];
    const float* b_mlp = (const float*)d_in[22];
    const float* W_fc  = (const float*)d_in[25];
    const float* b_fc  = (const float*)d_in[26];
    const float* W_ih  = (const float*)d_in[27];
    const float* b_ih  = (const float*)d_in[28];
    const float* W_ic  = (const float*)d_in[29];
    const float* b_ic  = (const float*)d_in[30];
    const float* W_iC  = (const float*)d_in[31];
    const float* b_iC  = (const float*)d_in[32];

    float* out = (float*)d_out;
    float* out_pred  = out;
    float* out_alpha = out + (size_t)Bz * TMz * Vz;
    float* out_order = out_alpha + (size_t)Bz * TMz * 1024;

    float* w = (float*)d_ws;
    float* ph   = w + WS_PH;
    float* pcp  = w + WS_PC;
    float* att1 = w + WS_ATT1;
    float* expe = w + WS_EXPE;
    float* zpart= w + WS_ZPART;
    float* awfp = w + WS_AWFP;
    float* gwh  = w + WS_GWH;
    float* hst  = w + WS_HST;
    float* cst  = w + WS_CST;
    float* Cst  = w + WS_CSTB;
    int*   ordp = (int*)(w + WS_INTS);
    int*   slp  = ordp + 32;
    int*   bar  = slp + 32;
    float* pC   = w + WS_PCHC;

    k_sort<<<1, 64, 0, stream>>>(lens, out_order, ordp, slp, bar);
    k_gemv2<<<512, 256, 0, stream>>>(info, ordp, W_ih, W_ic, ph, pcp);
    k_gemvC<<<128, 256, 0, stream>>>(rel, ordp, W_iC, pC);
    k_reduce3<<<96, 256, 0, stream>>>(ph, pcp, pC, b_ih, b_ic, b_iC, hst, cst, Cst);
    k_att1<<<1024, 256, 0, stream>>>(info, ordp, W_enc, b_enc, att1);

    KArgs ka;
    ka.info = info; ka.emb = emb; ka.W_dec = W_dec; ka.b_dec = b_dec;
    ka.W_full = W_full; ka.b_full = b_full;
    ka.W_i = W_i; ka.W_f = W_f; ka.W_o = W_o; ka.W_g1 = W_g1; ka.W_g2 = W_g2;
    ka.b_i = b_i; ka.b_f = b_f; ka.b_o = b_o; ka.b_g1 = b_g1; ka.b_g2 = b_g2;
    ka.W_mlp = W_mlp; ka.b_mlp = b_mlp; ka.W_fc = W_fc; ka.b_fc = b_fc;
    ka.caps = caps;
    ka.att1 = att1; ka.expe = expe; ka.zpart = zpart; ka.awfp = awfp; ka.gwh = gwh;
    ka.hst = hst; ka.cst = cst; ka.Cst = Cst;
    ka.ord = ordp; ka.slp = slp; ka.bar = bar;
    ka.out_pred = out_pred; ka.out_alpha = out_alpha;

    k_steps<<<256, 256, 0, stream>>>(ka);
}

// Round 4
// 6023.836 us; speedup vs baseline: 4.2923x; 4.2923x over previous
//
#include <hip/hip_runtime.h>
#include <math.h>

#define Bz 32
#define Tz 20
#define TMz 19
#define Vz 10000
#define INFLAT 262144   // P*D
#define RELSZ 16384
#define NBLK 256

// workspace float offsets
#define WS_PH     0
#define WS_PC     4194304
#define WS_ATT1   0              // reuses ph/pc region after k_reduce3
#define WS_EXPE   8388608
#define WS_ZPART  8421376
#define WS_AWFP   8421632        // 8*32*256 = 65536
#define WS_GWH    8487168        // 5*6*32*256 = 245760
#define WS_HST    8732928
#define WS_CST    8741120
#define WS_CSTB   8749312
#define WS_INTS   8757504        // ordp(32) slp(32) bar(8)
#define WS_PCHC   8757632        // 128*32*256 = 1048576 -> end 9806208 (~39.2MB)

__device__ __forceinline__ float sigm(float x) { return 1.0f / (1.0f + expf(-x)); }

__device__ __forceinline__ void gl_lds16(const float* g, float* l) {
    __builtin_amdgcn_global_load_lds(
        (const __attribute__((address_space(1))) unsigned int*)g,
        (__attribute__((address_space(3))) unsigned int*)l,
        16, 0, 0);
}

// software grid barrier: bar[0]=arrive counter, bar[1]=generation.
// Release fence once before arrive; RELAXED polling (agent-scope loads bypass
// the non-coherent per-XCD L2s via scope-determined cache bits, so no per-poll
// invalidation); acquire fence once after exit.
__device__ __forceinline__ void gbar(int* bar) {
    __syncthreads();
    if (threadIdx.x == 0) {
        __builtin_amdgcn_fence(__ATOMIC_RELEASE, "agent");
        int gen = __hip_atomic_load(&bar[1], __ATOMIC_RELAXED, __HIP_MEMORY_SCOPE_AGENT);
        int prev = __hip_atomic_fetch_add(&bar[0], 1, __ATOMIC_RELAXED, __HIP_MEMORY_SCOPE_AGENT);
        if (prev == NBLK - 1) {
            __hip_atomic_store(&bar[0], 0, __ATOMIC_RELAXED, __HIP_MEMORY_SCOPE_AGENT);
            __hip_atomic_store(&bar[1], gen + 1, __ATOMIC_RELAXED, __HIP_MEMORY_SCOPE_AGENT);
        } else {
            while (__hip_atomic_load(&bar[1], __ATOMIC_RELAXED, __HIP_MEMORY_SCOPE_AGENT) == gen) {
                __builtin_amdgcn_s_sleep(2);
            }
        }
        __builtin_amdgcn_fence(__ATOMIC_ACQUIRE, "agent");
    }
    __syncthreads();
}

// ---------------- sort + barrier init ----------------
__global__ void k_sort(const int* __restrict__ lens, float* __restrict__ out_order,
                       int* __restrict__ ord, int* __restrict__ sentlen, int* __restrict__ bar) {
    if (threadIdx.x == 0 && blockIdx.x == 0) {
        bar[0] = 0; bar[1] = 0;
        int l[Bz]; bool used[Bz];
        for (int b = 0; b < Bz; ++b) { l[b] = lens[b]; used[b] = false; }
        for (int i = 0; i < Bz; ++i) {
            int best = -1;
            for (int j = 0; j < Bz; ++j)
                if (!used[j] && (best < 0 || l[j] > l[best])) best = j;
            used[best] = true;
            ord[i] = best;
            sentlen[i] = l[best] - 1;
            out_order[i] = (float)best;
        }
    }
}

// ---------------- h0,c0: flat(32,262144) @ W_ih / W_ic ----------------
__global__ __launch_bounds__(256) void k_gemv2(const float* __restrict__ X, const int* __restrict__ ord,
                                               const float* __restrict__ W1, const float* __restrict__ W2,
                                               float* __restrict__ p1, float* __restrict__ p2) {
    __shared__ __align__(16) float wlds[8192];      // 2 slots x (8 rows x 256 x 2 mats)
    __shared__ __align__(16) float xsT[256 * 36];   // [k 0..255][b 0..31] pad 36
    __shared__ int ords[32];
    int tid = threadIdx.x;
    int wv = tid >> 6, ln = tid & 63;
    size_t k0 = (size_t)blockIdx.x * 512;

    if (tid < 32) ords[tid] = ord[tid];
    __syncthreads();

    auto stage_xs = [&](int hh) {
        for (int idx = tid; idx < 2048; idx += 256) {
            int b = idx >> 6, kq = idx & 63;
            float4 v = *(const float4*)&X[(size_t)ords[b] * INFLAT + k0 + (size_t)hh * 256 + kq * 4];
            xsT[(kq * 4 + 0) * 36 + b] = v.x;
            xsT[(kq * 4 + 1) * 36 + b] = v.y;
            xsT[(kq * 4 + 2) * 36 + b] = v.z;
            xsT[(kq * 4 + 3) * 36 + b] = v.w;
        }
    };
    auto issue = [&](int n) {
        int slot = n & 1;
        size_t krow = k0 + (size_t)n * 8 + wv * 2;
        const float* g1 = W1 + krow * 256 + ln * 4;
        const float* g2 = W2 + krow * 256 + ln * 4;
        float* l1 = &wlds[slot * 4096 + (wv * 2) * 256 + ln * 4];
        float* l2 = &wlds[slot * 4096 + 2048 + (wv * 2) * 256 + ln * 4];
        gl_lds16(g1, l1);
        gl_lds16(g2, l2);
        gl_lds16(g1 + 256, l1 + 256);
        gl_lds16(g2 + 256, l2 + 256);
    };

    float ah[32], ac[32];
#pragma unroll
    for (int b = 0; b < 32; ++b) { ah[b] = 0.f; ac[b] = 0.f; }

    stage_xs(0);
    issue(0);

#pragma unroll 1
    for (int c = 0; c < 64; ++c) {
        if (c == 32) stage_xs(1);
        if (c + 1 < 64) {
            issue(c + 1);
            asm volatile("s_waitcnt vmcnt(4)" ::: "memory");
        } else {
            asm volatile("s_waitcnt vmcnt(0)" ::: "memory");
        }
        __syncthreads();
        int slot = c & 1;
        int xb0 = (c & 31) * 8;
#pragma unroll
        for (int kk = 0; kk < 8; ++kk) {
            float w1 = wlds[slot * 4096 + kk * 256 + tid];
            float w2 = wlds[slot * 4096 + 2048 + kk * 256 + tid];
            const float4* xr = (const float4*)&xsT[(xb0 + kk) * 36];
#pragma unroll
            for (int bq = 0; bq < 8; ++bq) {
                float4 x4 = xr[bq];
                ah[bq * 4 + 0] += x4.x * w1; ac[bq * 4 + 0] += x4.x * w2;
                ah[bq * 4 + 1] += x4.y * w1; ac[bq * 4 + 1] += x4.y * w2;
                ah[bq * 4 + 2] += x4.z * w1; ac[bq * 4 + 2] += x4.z * w2;
                ah[bq * 4 + 3] += x4.w * w1; ac[bq * 4 + 3] += x4.w * w2;
            }
        }
        __syncthreads();
    }
#pragma unroll
    for (int b = 0; b < 32; ++b) {
        size_t o = ((size_t)blockIdx.x * 32 + b) * 256 + tid;
        p1[o] = ah[b];
        p2[o] = ac[b];
    }
}

// ---------------- C0: rel(32,16384) @ W_iC, split-K ----------------
__global__ __launch_bounds__(256) void k_gemvC(const float* __restrict__ R, const int* __restrict__ ord,
                                               const float* __restrict__ W, float* __restrict__ p) {
    __shared__ float xs[32 * 128];
    __shared__ int ords[32];
    int tid = threadIdx.x, bx = blockIdx.x;
    if (tid < 32) ords[tid] = ord[tid];
    __syncthreads();
    int k0 = bx * 128;
    for (int idx = tid; idx < 32 * 128; idx += 256) {
        int b = idx >> 7, kk = idx & 127;
        xs[idx] = R[(size_t)ords[b] * RELSZ + k0 + kk];
    }
    __syncthreads();
    float acc[32];
#pragma unroll
    for (int b = 0; b < 32; ++b) acc[b] = 0.f;
    for (int kk = 0; kk < 128; ++kk) {
        float w = W[(size_t)(k0 + kk) * 256 + tid];
#pragma unroll
        for (int b = 0; b < 32; ++b) acc[b] += xs[b * 128 + kk] * w;
    }
#pragma unroll
    for (int b = 0; b < 32; ++b) p[((size_t)bx * 32 + b) * 256 + tid] = acc[b];
}

// ---------------- combined split-K reduces: h0, c0, C0 ----------------
__global__ __launch_bounds__(256) void k_reduce3(const float* __restrict__ ph, const float* __restrict__ pc,
                                                 const float* __restrict__ pC,
                                                 const float* __restrict__ b_ih, const float* __restrict__ b_ic,
                                                 const float* __restrict__ b_iC,
                                                 float* __restrict__ hst, float* __restrict__ cst,
                                                 float* __restrict__ Cst) {
    int which = blockIdx.x >> 5, b = blockIdx.x & 31, j = threadIdx.x;
    if (which == 0) {
        float s0 = b_ih[j], s1 = 0.f, s2 = 0.f, s3 = 0.f;
        for (int c = 0; c < 512; c += 4) {
            s0 += ph[((size_t)((c + 0) * 32 + b)) * 256 + j];
            s1 += ph[((size_t)((c + 1) * 32 + b)) * 256 + j];
            s2 += ph[((size_t)((c + 2) * 32 + b)) * 256 + j];
            s3 += ph[((size_t)((c + 3) * 32 + b)) * 256 + j];
        }
        hst[b * 256 + j] = s0 + s1 + s2 + s3;
    } else if (which == 1) {
        float s0 = b_ic[j], s1 = 0.f, s2 = 0.f, s3 = 0.f;
        for (int c = 0; c < 512; c += 4) {
            s0 += pc[((size_t)((c + 0) * 32 + b)) * 256 + j];
            s1 += pc[((size_t)((c + 1) * 32 + b)) * 256 + j];
            s2 += pc[((size_t)((c + 2) * 32 + b)) * 256 + j];
            s3 += pc[((size_t)((c + 3) * 32 + b)) * 256 + j];
        }
        cst[b * 256 + j] = s0 + s1 + s2 + s3;
    } else {
        float s0 = b_iC[j], s1 = 0.f, s2 = 0.f, s3 = 0.f;
        for (int c = 0; c < 128; c += 4) {
            s0 += pC[((size_t)((c + 0) * 32 + b)) * 256 + j];
            s1 += pC[((size_t)((c + 1) * 32 + b)) * 256 + j];
            s2 += pC[((size_t)((c + 2) * 32 + b)) * 256 + j];
            s3 += pC[((size_t)((c + 3) * 32 + b)) * 256 + j];
        }
        Cst[b * 256 + j] = s0 + s1 + s2 + s3;
    }
}

// ---------------- att1 = info_sorted @ W_enc + b_enc ----------------
__global__ __launch_bounds__(256) void k_att1(const float* __restrict__ info, const int* __restrict__ ord,
                                              const float* __restrict__ W, const float* __restrict__ bias,
                                              float* __restrict__ att1) {
    __shared__ __align__(16) float xsT[256 * 36];   // [k][row] pad 36
    int tid = threadIdx.x;
    int r0 = blockIdx.x * 32;
    int b = r0 >> 10, p0 = r0 & 1023;
    const float* src = info + (size_t)ord[b] * INFLAT + (size_t)p0 * 256;
    for (int idx = tid; idx < 2048; idx += 256) {
        int r = idx >> 6, kq = idx & 63;
        float4 v = *(const float4*)&src[r * 256 + kq * 4];
        xsT[(kq * 4 + 0) * 36 + r] = v.x;
        xsT[(kq * 4 + 1) * 36 + r] = v.y;
        xsT[(kq * 4 + 2) * 36 + r] = v.z;
        xsT[(kq * 4 + 3) * 36 + r] = v.w;
    }
    __syncthreads();
    float acc[32];
#pragma unroll
    for (int r = 0; r < 32; ++r) acc[r] = 0.f;
    for (int k = 0; k < 256; ++k) {
        float w = W[k * 256 + tid];
        const float4* xr = (const float4*)&xsT[k * 36];
#pragma unroll
        for (int rq = 0; rq < 8; ++rq) {
            float4 x4 = xr[rq];
            acc[rq * 4 + 0] += x4.x * w;
            acc[rq * 4 + 1] += x4.y * w;
            acc[rq * 4 + 2] += x4.z * w;
            acc[rq * 4 + 3] += x4.w * w;
        }
    }
    float bj = bias[tid];
#pragma unroll
    for (int r = 0; r < 32; ++r) att1[((size_t)(r0 + r)) * 256 + tid] = acc[r] + bj;
}

// ---------------- fused steps kernel (software grid barrier) ----------------
struct KArgs {
    const float *info, *emb, *W_dec, *b_dec, *W_full, *b_full;
    const float *W_i, *W_f, *W_o, *W_g1, *W_g2;
    const float *b_i, *b_f, *b_o, *b_g1, *b_g2;
    const float *W_mlp, *b_mlp, *W_fc, *b_fc;
    const int *caps;
    float *att1, *expe, *zpart, *awfp, *gwh, *hst, *cst, *Cst;
    const int *ord, *slp;
    int *bar;
    float *out_pred, *out_alpha;
};

// LDS map (floats): [0..8191] h copy (phase A) / [0..255] awfs + [256..767] cc (phase D)
// [8192..8447] at2, [8448..8575] local expe, [8576..8579] zs, [8704..12799] xb
__device__ void pred_task(const KArgs& a, const float* sm, int tile, int tm1) {
    int tid = threadIdx.x;
    int col = tile * 64 + (tid & 63), bg = tid >> 6;
    if (col >= Vz) return;
    float acc[8] = {0.f, 0.f, 0.f, 0.f, 0.f, 0.f, 0.f, 0.f};
    for (int jq = 0; jq < 64; ++jq) {
        float w0 = a.W_fc[(size_t)(jq * 4 + 0) * Vz + col];
        float w1 = a.W_fc[(size_t)(jq * 4 + 1) * Vz + col];
        float w2 = a.W_fc[(size_t)(jq * 4 + 2) * Vz + col];
        float w3 = a.W_fc[(size_t)(jq * 4 + 3) * Vz + col];
#pragma unroll
        for (int bi = 0; bi < 8; ++bi) {
            float4 h4 = *(const float4*)&sm[(bg * 8 + bi) * 256 + jq * 4];
            acc[bi] += h4.x * w0 + h4.y * w1 + h4.z * w2 + h4.w * w3;
        }
    }
    float bv = a.b_fc[col];
#pragma unroll
    for (int bi = 0; bi < 8; ++bi) {
        int b = bg * 8 + bi;
        float r = (a.slp[b] > tm1) ? (acc[bi] + bv) : 0.f;
        a.out_pred[((size_t)b * TMz + tm1) * Vz + col] = r;
    }
}

__device__ void gwh_task(const KArgs& a, float* sm, int tk, int t) {
    int tid = threadIdx.x;
    int g = tk / 24, r = tk % 24, ct = r / 6, ks = r % 6;
    const float* Wg = (g == 0) ? a.W_i : (g == 1) ? a.W_f : (g == 2) ? a.W_o : (g == 3) ? a.W_g1 : a.W_g2;
    int col = ct * 64 + (tid & 63), bg = tid >> 6;
    float* xb = sm + 8704;
    int wbase, hoff = 0;
    if (ks < 4) {
        wbase = ks * 128;
        for (int idx = tid; idx < 1024; idx += 256) {
            int b = idx >> 5, kq = idx & 31;
            int cap = a.caps[a.ord[b] * Tz + t];
            float4 v = *(const float4*)&a.emb[(size_t)cap * 512 + ks * 128 + kq * 4];
            *(float4*)&xb[b * 128 + kq * 4] = v;
        }
        __syncthreads();
    } else {
        wbase = 768 + (ks - 4) * 128;
        hoff = (ks - 4) * 128;
    }
    float acc[8] = {0.f, 0.f, 0.f, 0.f, 0.f, 0.f, 0.f, 0.f};
    for (int kq = 0; kq < 32; ++kq) {
        float w0 = Wg[(size_t)(wbase + kq * 4 + 0) * 256 + col];
        float w1 = Wg[(size_t)(wbase + kq * 4 + 1) * 256 + col];
        float w2 = Wg[(size_t)(wbase + kq * 4 + 2) * 256 + col];
        float w3 = Wg[(size_t)(wbase + kq * 4 + 3) * 256 + col];
#pragma unroll
        for (int bi = 0; bi < 8; ++bi) {
            int b = bg * 8 + bi;
            const float* xr = (ks < 4) ? &xb[b * 128] : &sm[b * 256 + hoff];
            float4 x4 = *(const float4*)&xr[kq * 4];
            acc[bi] += x4.x * w0 + x4.y * w1 + x4.z * w2 + x4.w * w3;
        }
    }
#pragma unroll
    for (int bi = 0; bi < 8; ++bi)
        a.gwh[((size_t)((g * 6 + ks) * 32 + bg * 8 + bi)) * 256 + col] = acc[bi];
}

__global__ __launch_bounds__(256) void k_steps(KArgs a) {
    __shared__ __align__(16) float sm[12800];
    int bid = blockIdx.x, tid = threadIdx.x;

    for (int t = 0; t < TMz; ++t) {
        // ---------- Phase A ----------
        for (int i = tid; i < 2048; i += 256) ((float4*)sm)[i] = ((const float4*)a.hst)[i];
        __syncthreads();
        int b = bid >> 3, pc = bid & 7;
        int ordb = a.ord[b];
        {
            // at2 (redundant per pc-block)
            float v = a.b_dec[tid];
            const float* hb = sm + b * 256;
            for (int k = 0; k < 256; k += 4) {
                float4 h4 = *(const float4*)&hb[k];
                v += h4.x * a.W_dec[(k + 0) * 256 + tid] + h4.y * a.W_dec[(k + 1) * 256 + tid]
                   + h4.z * a.W_dec[(k + 2) * 256 + tid] + h4.w * a.W_dec[(k + 3) * 256 + tid];
            }
            sm[8192 + tid] = v;
        }
        __syncthreads();
        {
            int wv = tid >> 6, ln = tid & 63;
            float4 wf4 = *(const float4*)&a.W_full[ln * 4];
            float4 a24 = *(const float4*)&sm[8192 + ln * 4];
            float bf = a.b_full[0];
            float zac = 0.f;
            for (int i = 0; i < 32; ++i) {
                int p = pc * 128 + wv * 32 + i;
                float4 r4 = *(const float4*)&a.att1[((size_t)(b * 1024 + p)) * 256 + ln * 4];
                float s = fmaxf(r4.x + a24.x, 0.f) * wf4.x + fmaxf(r4.y + a24.y, 0.f) * wf4.y
                        + fmaxf(r4.z + a24.z, 0.f) * wf4.z + fmaxf(r4.w + a24.w, 0.f) * wf4.w;
                s += __shfl_down(s, 32); s += __shfl_down(s, 16); s += __shfl_down(s, 8);
                s += __shfl_down(s, 4);  s += __shfl_down(s, 2);  s += __shfl_down(s, 1);
                if (ln == 0) {
                    float ex = expf(s + bf);
                    a.expe[b * 1024 + p] = ex;
                    sm[8448 + wv * 32 + i] = ex;
                    zac += ex;
                }
            }
            if (ln == 0) sm[8576 + wv] = zac;
        }
        __syncthreads();
        if (tid == 0) a.zpart[b * 8 + pc] = sm[8576] + sm[8577] + sm[8578] + sm[8579];
        {
            // awf partial over this block's 128 p-rows (unnormalized)
            const float* ib = a.info + (size_t)ordb * INFLAT + (size_t)(pc * 128) * 256;
            float q0 = 0.f, q1 = 0.f, q2 = 0.f, q3 = 0.f;
            for (int i = 0; i < 128; i += 4) {
                q0 += sm[8448 + i + 0] * ib[(size_t)(i + 0) * 256 + tid];
                q1 += sm[8448 + i + 1] * ib[(size_t)(i + 1) * 256 + tid];
                q2 += sm[8448 + i + 2] * ib[(size_t)(i + 2) * 256 + tid];
                q3 += sm[8448 + i + 3] * ib[(size_t)(i + 3) * 256 + tid];
            }
            a.awfp[((size_t)(b * 8 + pc)) * 256 + tid] = (q0 + q1) + (q2 + q3);
        }
        if (t > 0 && bid < 157) pred_task(a, sm, bid, t - 1);
        if (bid >= 136) gwh_task(a, sm, bid - 136, t);
        gbar(a.bar);

        // ---------- Phase D ----------
        if (bid < 32) {
            int bb = bid, j = tid;
            float Z = 0.f;
#pragma unroll
            for (int c = 0; c < 8; ++c) Z += a.zpart[bb * 8 + c];
            float invZ = 1.0f / Z;
            float aw = 0.f;
#pragma unroll
            for (int c = 0; c < 8; ++c) aw += a.awfp[((size_t)(bb * 8 + c)) * 256 + j];
            sm[j] = aw * invZ;   // awfs
            float am = (a.slp[bb] > t) ? invZ : 0.f;
            const float* eb = a.expe + bb * 1024;
            float* oal = a.out_alpha + ((size_t)bb * TMz + t) * 1024;
            for (int p = tid; p < 1024; p += 256) oal[p] = eb[p] * am;
            __syncthreads();

            float gs[5];
#pragma unroll
            for (int g = 0; g < 5; ++g) {
                const float* Wg = (g == 0) ? a.W_i : (g == 1) ? a.W_f : (g == 2) ? a.W_o : (g == 3) ? a.W_g1 : a.W_g2;
                const float* bg = (g == 0) ? a.b_i : (g == 1) ? a.b_f : (g == 2) ? a.b_o : (g == 3) ? a.b_g1 : a.b_g2;
                float s = bg[j];
#pragma unroll
                for (int ks = 0; ks < 6; ++ks) s += a.gwh[((size_t)((g * 6 + ks) * 32 + bb)) * 256 + j];
                float s0 = 0.f, s1 = 0.f, s2 = 0.f, s3 = 0.f;
                for (int kq = 0; kq < 64; ++kq) {
                    float4 x4 = *(const float4*)&sm[kq * 4];
                    s0 += x4.x * Wg[(size_t)(512 + kq * 4 + 0) * 256 + j];
                    s1 += x4.y * Wg[(size_t)(512 + kq * 4 + 1) * 256 + j];
                    s2 += x4.z * Wg[(size_t)(512 + kq * 4 + 2) * 256 + j];
                    s3 += x4.w * Wg[(size_t)(512 + kq * 4 + 3) * 256 + j];
                }
                gs[g] = s + (s0 + s1) + (s2 + s3);
            }
            float iv = sigm(gs[0]), fv = sigm(gs[1]), ov = sigm(gs[2]);
            float g1 = tanhf(gs[3]), g2 = tanhf(gs[4]);
            float nc = fv * a.cst[bb * 256 + j] + iv * g1;
            float nC = fv * a.Cst[bb * 256 + j] + iv * g2;
            a.cst[bb * 256 + j] = nc;
            a.Cst[bb * 256 + j] = nC;
            sm[256 + j] = nc;
            sm[512 + j] = nC;
            __syncthreads();
            float m0 = a.b_mlp[j], m1 = 0.f, m2 = 0.f, m3 = 0.f;
            for (int kq = 0; kq < 128; ++kq) {
                float4 c4 = *(const float4*)&sm[256 + kq * 4];
                m0 += c4.x * a.W_mlp[(size_t)(kq * 4 + 0) * 256 + j];
                m1 += c4.y * a.W_mlp[(size_t)(kq * 4 + 1) * 256 + j];
                m2 += c4.z * a.W_mlp[(size_t)(kq * 4 + 2) * 256 + j];
                m3 += c4.w * a.W_mlp[(size_t)(kq * 4 + 3) * 256 + j];
            }
            a.hst[bb * 256 + j] = ov * tanhf((m0 + m1) + (m2 + m3));
        }
        gbar(a.bar);
    }

    // epilogue: pred for t = 18
    for (int i = tid; i < 2048; i += 256) ((float4*)sm)[i] = ((const float4*)a.hst)[i];
    __syncthreads();
    if (bid < 157) pred_task(a, sm, bid, TMz - 1);
}

extern "C" void kernel_launch(void* const* d_in, const int* in_sizes, int n_in,
                              void* d_out, int out_size, void* d_ws, size_t ws_size,
                              hipStream_t stream) {
    const float* info  = (const float*)d_in[0];
    const float* rel   = (const float*)d_in[1];
    const int*   caps  = (const int*)d_in[2];
    const int*   lens  = (const int*)d_in[3];
    const float* emb   = (const float*)d_in[4];
    const float* W_enc = (const float*)d_in[5];
    const float* b_enc = (const float*)d_in[6];
    const float* W_dec = (const float*)d_in[7];
    const float* b_dec = (const float*)d_in[8];
    const float* W_full= (const float*)d_in[9];
    const float* b_full= (const float*)d_in[10];
    const float* W_i   = (const float*)d_in[11];
    const float* b_i   = (const float*)d_in[12];
    const float* W_f   = (const float*)d_in[13];
    const float* b_f   = (const float*)d_in[14];
    const float* W_o   = (const float*)d_in[15];
    const float* b_o   = (const float*)d_in[16];
    const float* W_g1  = (const float*)d_in[17];
    const float* b_g1  = (const float*)d_in[18];
    const float* W_g2  = (const float*)d_in[19];
    const float* b_g2  = (const float*)d_in[20];
    const float* W_mlp = (const float*)d_in[21];
    const float* b_mlp = (const float*)d_in[22];
    const float* W_fc  = (const float*)d_in[25];
    const float* b_fc  = (const float*)d_in[26];
    const float* W_ih  = (const float*)d_in[27];
    const float* b_ih  = (const float*)d_in[28];
    const float* W_ic  = (const float*)d_in[29];
    const float* b_ic  = (const float*)d_in[30];
    const float* W_iC  = (const float*)d_in[31];
    const float* b_iC  = (const float*)d_in[32];

    float* out = (float*)d_out;
    float* out_pred  = out;
    float* out_alpha = out + (size_t)Bz * TMz * Vz;
    float* out_order = out_alpha + (size_t)Bz * TMz * 1024;

    float* w = (float*)d_ws;
    float* ph   = w + WS_PH;
    float* pcp  = w + WS_PC;
    float* att1 = w + WS_ATT1;
    float* expe = w + WS_EXPE;
    float* zpart= w + WS_ZPART;
    float* awfp = w + WS_AWFP;
    float* gwh  = w + WS_GWH;
    float* hst  = w + WS_HST;
    float* cst  = w + WS_CST;
    float* Cst  = w + WS_CSTB;
    int*   ordp = (int*)(w + WS_INTS);
    int*   slp  = ordp + 32;
    int*   bar  = slp + 32;
    float* pC   = w + WS_PCHC;

    k_sort<<<1, 64, 0, stream>>>(lens, out_order, ordp, slp, bar);
    k_gemv2<<<512, 256, 0, stream>>>(info, ordp, W_ih, W_ic, ph, pcp);
    k_gemvC<<<128, 256, 0, stream>>>(rel, ordp, W_iC, pC);
    k_reduce3<<<96, 256, 0, stream>>>(ph, pcp, pC, b_ih, b_ic, b_iC, hst, cst, Cst);
    k_att1<<<1024, 256, 0, stream>>>(info, ordp, W_enc, b_enc, att1);

    KArgs ka;
    ka.info = info; ka.emb = emb; ka.W_dec = W_dec; ka.b_dec = b_dec;
    ka.W_full = W_full; ka.b_full = b_full;
    ka.W_i = W_i; ka.W_f = W_f; ka.W_o = W_o; ka.W_g1 = W_g1; ka.W_g2 = W_g2;
    ka.b_i = b_i; ka.b_f = b_f; ka.b_o = b_o; ka.b_g1 = b_g1; ka.b_g2 = b_g2;
    ka.W_mlp = W_mlp; ka.b_mlp = b_mlp; ka.W_fc = W_fc; ka.b_fc = b_fc;
    ka.caps = caps;
    ka.att1 = att1; ka.expe = expe; ka.zpart = zpart; ka.awfp = awfp; ka.gwh = gwh;
    ka.hst = hst; ka.cst = cst; ka.Cst = Cst;
    ka.ord = ordp; ka.slp = slp; ka.bar = bar;
    ka.out_pred = out_pred; ka.out_alpha = out_alpha;

    k_steps<<<256, 256, 0, stream>>>(ka);
}

// Round 5
// 3261.775 us; speedup vs baseline: 7.9271x; 1.8468x over previous
//
#include <hip/hip_runtime.h>
#include <math.h>

#define Bz 32
#define Tz 20
#define TMz 19
#define Vz 10000
#define INFLAT 262144   // P*D
#define RELSZ 16384
#define NBLK 512

// workspace float offsets
#define WS_PH     0
#define WS_PC     4194304
#define WS_ATT1   0              // reuses ph/pc region after k_reduce3
#define WS_EXPE   8388608        // 32768
#define WS_ZPART  8421376        // 512 (32 b x 16 pc)
#define WS_AWFP   8421888        // 16*32*256 = 131072
#define WS_GWH    8552960        // 5*6*32*256 = 245760
#define WS_GSG    8798720        // 5*32*256 = 40960
#define WS_HST    8839680        // 8192
#define WS_CST    8847872        // 8192
#define WS_CSTB   8856064        // 8192
#define WS_INTS   8864256        // ordp[32] slp[32] root@64 slots@128..640
#define WS_PCHC   8865280        // 128*32*256 = 1048576 -> end 9913856 (~39.7MB)

__device__ __forceinline__ float sigm(float x) { return 1.0f / (1.0f + expf(-x)); }

__device__ __forceinline__ void gl_lds16(const float* g, float* l) {
    __builtin_amdgcn_global_load_lds(
        (const __attribute__((address_space(1))) unsigned int*)g,
        (__attribute__((address_space(3))) unsigned int*)l,
        16, 0, 0);
}

// Slot-based grid barrier: no atomic contention. Each block stores gen to its
// own slot; block 0's threads poll all slots in parallel, then publish root.
__device__ __forceinline__ void gbar(int* slots, int* root, int gen) {
    __syncthreads();
    if (blockIdx.x == 0) {
        if (threadIdx.x == 0) __builtin_amdgcn_fence(__ATOMIC_RELEASE, "agent");
        int i0 = threadIdx.x;
        int i1 = threadIdx.x + 256;
        if (i0 != 0) {
            while (__hip_atomic_load(&slots[i0], __ATOMIC_RELAXED, __HIP_MEMORY_SCOPE_AGENT) < gen)
                __builtin_amdgcn_s_sleep(1);
        }
        while (__hip_atomic_load(&slots[i1], __ATOMIC_RELAXED, __HIP_MEMORY_SCOPE_AGENT) < gen)
            __builtin_amdgcn_s_sleep(1);
        __syncthreads();
        if (threadIdx.x == 0) {
            __hip_atomic_store(root, gen, __ATOMIC_RELAXED, __HIP_MEMORY_SCOPE_AGENT);
            __builtin_amdgcn_fence(__ATOMIC_ACQUIRE, "agent");
        }
    } else {
        if (threadIdx.x == 0) {
            __builtin_amdgcn_fence(__ATOMIC_RELEASE, "agent");
            __hip_atomic_store(&slots[blockIdx.x], gen, __ATOMIC_RELAXED, __HIP_MEMORY_SCOPE_AGENT);
            while (__hip_atomic_load(root, __ATOMIC_RELAXED, __HIP_MEMORY_SCOPE_AGENT) < gen)
                __builtin_amdgcn_s_sleep(2);
            __builtin_amdgcn_fence(__ATOMIC_ACQUIRE, "agent");
        }
    }
    __syncthreads();
}

// ---------------- sort + barrier init ----------------
__global__ void k_sort(const int* __restrict__ lens, float* __restrict__ out_order,
                       int* __restrict__ ord, int* __restrict__ sentlen, int* __restrict__ barmem) {
    if (threadIdx.x == 0 && blockIdx.x == 0) {
        for (int i = 0; i < 64 + NBLK; ++i) barmem[i] = 0;   // root@0 pad, slots@64
        int l[Bz]; bool used[Bz];
        for (int b = 0; b < Bz; ++b) { l[b] = lens[b]; used[b] = false; }
        for (int i = 0; i < Bz; ++i) {
            int best = -1;
            for (int j = 0; j < Bz; ++j)
                if (!used[j] && (best < 0 || l[j] > l[best])) best = j;
            used[best] = true;
            ord[i] = best;
            sentlen[i] = l[best] - 1;
            out_order[i] = (float)best;
        }
    }
}

// ---------------- h0,c0: flat(32,262144) @ W_ih / W_ic ----------------
__global__ __launch_bounds__(256) void k_gemv2(const float* __restrict__ X, const int* __restrict__ ord,
                                               const float* __restrict__ W1, const float* __restrict__ W2,
                                               float* __restrict__ p1, float* __restrict__ p2) {
    __shared__ __align__(16) float wlds[8192];
    __shared__ __align__(16) float xsT[256 * 36];
    __shared__ int ords[32];
    int tid = threadIdx.x;
    int wv = tid >> 6, ln = tid & 63;
    size_t k0 = (size_t)blockIdx.x * 512;

    if (tid < 32) ords[tid] = ord[tid];
    __syncthreads();

    auto stage_xs = [&](int hh) {
        for (int idx = tid; idx < 2048; idx += 256) {
            int b = idx >> 6, kq = idx & 63;
            float4 v = *(const float4*)&X[(size_t)ords[b] * INFLAT + k0 + (size_t)hh * 256 + kq * 4];
            xsT[(kq * 4 + 0) * 36 + b] = v.x;
            xsT[(kq * 4 + 1) * 36 + b] = v.y;
            xsT[(kq * 4 + 2) * 36 + b] = v.z;
            xsT[(kq * 4 + 3) * 36 + b] = v.w;
        }
    };
    auto issue = [&](int n) {
        int slot = n & 1;
        size_t krow = k0 + (size_t)n * 8 + wv * 2;
        const float* g1 = W1 + krow * 256 + ln * 4;
        const float* g2 = W2 + krow * 256 + ln * 4;
        float* l1 = &wlds[slot * 4096 + (wv * 2) * 256 + ln * 4];
        float* l2 = &wlds[slot * 4096 + 2048 + (wv * 2) * 256 + ln * 4];
        gl_lds16(g1, l1);
        gl_lds16(g2, l2);
        gl_lds16(g1 + 256, l1 + 256);
        gl_lds16(g2 + 256, l2 + 256);
    };

    float ah[32], ac[32];
#pragma unroll
    for (int b = 0; b < 32; ++b) { ah[b] = 0.f; ac[b] = 0.f; }

    stage_xs(0);
    issue(0);

#pragma unroll 1
    for (int c = 0; c < 64; ++c) {
        if (c == 32) stage_xs(1);
        if (c + 1 < 64) {
            issue(c + 1);
            asm volatile("s_waitcnt vmcnt(4)" ::: "memory");
        } else {
            asm volatile("s_waitcnt vmcnt(0)" ::: "memory");
        }
        __syncthreads();
        int slot = c & 1;
        int xb0 = (c & 31) * 8;
#pragma unroll
        for (int kk = 0; kk < 8; ++kk) {
            float w1 = wlds[slot * 4096 + kk * 256 + tid];
            float w2 = wlds[slot * 4096 + 2048 + kk * 256 + tid];
            const float4* xr = (const float4*)&xsT[(xb0 + kk) * 36];
#pragma unroll
            for (int bq = 0; bq < 8; ++bq) {
                float4 x4 = xr[bq];
                ah[bq * 4 + 0] += x4.x * w1; ac[bq * 4 + 0] += x4.x * w2;
                ah[bq * 4 + 1] += x4.y * w1; ac[bq * 4 + 1] += x4.y * w2;
                ah[bq * 4 + 2] += x4.z * w1; ac[bq * 4 + 2] += x4.z * w2;
                ah[bq * 4 + 3] += x4.w * w1; ac[bq * 4 + 3] += x4.w * w2;
            }
        }
        __syncthreads();
    }
#pragma unroll
    for (int b = 0; b < 32; ++b) {
        size_t o = ((size_t)blockIdx.x * 32 + b) * 256 + tid;
        p1[o] = ah[b];
        p2[o] = ac[b];
    }
}

// ---------------- C0: rel(32,16384) @ W_iC, split-K ----------------
__global__ __launch_bounds__(256) void k_gemvC(const float* __restrict__ R, const int* __restrict__ ord,
                                               const float* __restrict__ W, float* __restrict__ p) {
    __shared__ float xs[32 * 128];
    __shared__ int ords[32];
    int tid = threadIdx.x, bx = blockIdx.x;
    if (tid < 32) ords[tid] = ord[tid];
    __syncthreads();
    int k0 = bx * 128;
    for (int idx = tid; idx < 32 * 128; idx += 256) {
        int b = idx >> 7, kk = idx & 127;
        xs[idx] = R[(size_t)ords[b] * RELSZ + k0 + kk];
    }
    __syncthreads();
    float acc[32];
#pragma unroll
    for (int b = 0; b < 32; ++b) acc[b] = 0.f;
    for (int kk = 0; kk < 128; ++kk) {
        float w = W[(size_t)(k0 + kk) * 256 + tid];
#pragma unroll
        for (int b = 0; b < 32; ++b) acc[b] += xs[b * 128 + kk] * w;
    }
#pragma unroll
    for (int b = 0; b < 32; ++b) p[((size_t)bx * 32 + b) * 256 + tid] = acc[b];
}

// ---------------- combined split-K reduces: h0, c0, C0 ----------------
__global__ __launch_bounds__(256) void k_reduce3(const float* __restrict__ ph, const float* __restrict__ pc,
                                                 const float* __restrict__ pC,
                                                 const float* __restrict__ b_ih, const float* __restrict__ b_ic,
                                                 const float* __restrict__ b_iC,
                                                 float* __restrict__ hst, float* __restrict__ cst,
                                                 float* __restrict__ Cst) {
    int which = blockIdx.x >> 5, b = blockIdx.x & 31, j = threadIdx.x;
    if (which == 0) {
        float s0 = b_ih[j], s1 = 0.f, s2 = 0.f, s3 = 0.f;
        for (int c = 0; c < 512; c += 4) {
            s0 += ph[((size_t)((c + 0) * 32 + b)) * 256 + j];
            s1 += ph[((size_t)((c + 1) * 32 + b)) * 256 + j];
            s2 += ph[((size_t)((c + 2) * 32 + b)) * 256 + j];
            s3 += ph[((size_t)((c + 3) * 32 + b)) * 256 + j];
        }
        hst[b * 256 + j] = s0 + s1 + s2 + s3;
    } else if (which == 1) {
        float s0 = b_ic[j], s1 = 0.f, s2 = 0.f, s3 = 0.f;
        for (int c = 0; c < 512; c += 4) {
            s0 += pc[((size_t)((c + 0) * 32 + b)) * 256 + j];
            s1 += pc[((size_t)((c + 1) * 32 + b)) * 256 + j];
            s2 += pc[((size_t)((c + 2) * 32 + b)) * 256 + j];
            s3 += pc[((size_t)((c + 3) * 32 + b)) * 256 + j];
        }
        cst[b * 256 + j] = s0 + s1 + s2 + s3;
    } else {
        float s0 = b_iC[j], s1 = 0.f, s2 = 0.f, s3 = 0.f;
        for (int c = 0; c < 128; c += 4) {
            s0 += pC[((size_t)((c + 0) * 32 + b)) * 256 + j];
            s1 += pC[((size_t)((c + 1) * 32 + b)) * 256 + j];
            s2 += pC[((size_t)((c + 2) * 32 + b)) * 256 + j];
            s3 += pC[((size_t)((c + 3) * 32 + b)) * 256 + j];
        }
        Cst[b * 256 + j] = s0 + s1 + s2 + s3;
    }
}

// ---------------- att1 = info_sorted @ W_enc + b_enc ----------------
__global__ __launch_bounds__(256) void k_att1(const float* __restrict__ info, const int* __restrict__ ord,
                                              const float* __restrict__ W, const float* __restrict__ bias,
                                              float* __restrict__ att1) {
    __shared__ __align__(16) float xsT[256 * 36];
    int tid = threadIdx.x;
    int r0 = blockIdx.x * 32;
    int b = r0 >> 10, p0 = r0 & 1023;
    const float* src = info + (size_t)ord[b] * INFLAT + (size_t)p0 * 256;
    for (int idx = tid; idx < 2048; idx += 256) {
        int r = idx >> 6, kq = idx & 63;
        float4 v = *(const float4*)&src[r * 256 + kq * 4];
        xsT[(kq * 4 + 0) * 36 + r] = v.x;
        xsT[(kq * 4 + 1) * 36 + r] = v.y;
        xsT[(kq * 4 + 2) * 36 + r] = v.z;
        xsT[(kq * 4 + 3) * 36 + r] = v.w;
    }
    __syncthreads();
    float acc[32];
#pragma unroll
    for (int r = 0; r < 32; ++r) acc[r] = 0.f;
    for (int k = 0; k < 256; ++k) {
        float w = W[k * 256 + tid];
        const float4* xr = (const float4*)&xsT[k * 36];
#pragma unroll
        for (int rq = 0; rq < 8; ++rq) {
            float4 x4 = xr[rq];
            acc[rq * 4 + 0] += x4.x * w;
            acc[rq * 4 + 1] += x4.y * w;
            acc[rq * 4 + 2] += x4.z * w;
            acc[rq * 4 + 3] += x4.w * w;
        }
    }
    float bj = bias[tid];
#pragma unroll
    for (int r = 0; r < 32; ++r) att1[((size_t)(r0 + r)) * 256 + tid] = acc[r] + bj;
}

// ---------------- fused steps kernel ----------------
struct KArgs {
    const float *info, *emb, *W_dec, *b_dec, *W_full, *b_full;
    const float *W_i, *W_f, *W_o, *W_g1, *W_g2;
    const float *b_i, *b_f, *b_o, *b_g1, *b_g2;
    const float *W_mlp, *b_mlp, *W_fc, *b_fc;
    const int *caps;
    float *att1, *expe, *zpart, *awfp, *gwh, *gsg, *hst, *cst, *Cst;
    const int *ord, *slp;
    int *root, *slots;
    float *out_pred, *out_alpha;
};

// LDS map (floats): [0..8191] h copy | C: [0..255] nc, [256..511] nC, [512..767] ov,
// [768..1059] mred; A: [8192..8447] at2, [8448..8511] expe-local, [8576..8579] zs,
// [8704..12799] xb (gwh)
__device__ void pred_task(const KArgs& a, const float* sm, int tile, int tm1) {
    int tid = threadIdx.x;
    int col = tile * 64 + (tid & 63), bg = tid >> 6;
    if (col >= Vz) return;
    float acc[8] = {0.f, 0.f, 0.f, 0.f, 0.f, 0.f, 0.f, 0.f};
    for (int jq = 0; jq < 64; ++jq) {
        float w0 = a.W_fc[(size_t)(jq * 4 + 0) * Vz + col];
        float w1 = a.W_fc[(size_t)(jq * 4 + 1) * Vz + col];
        float w2 = a.W_fc[(size_t)(jq * 4 + 2) * Vz + col];
        float w3 = a.W_fc[(size_t)(jq * 4 + 3) * Vz + col];
#pragma unroll
        for (int bi = 0; bi < 8; ++bi) {
            float4 h4 = *(const float4*)&sm[(bg * 8 + bi) * 256 + jq * 4];
            acc[bi] += h4.x * w0 + h4.y * w1 + h4.z * w2 + h4.w * w3;
        }
    }
    float bv = a.b_fc[col];
#pragma unroll
    for (int bi = 0; bi < 8; ++bi) {
        int b = bg * 8 + bi;
        float r = (a.slp[b] > tm1) ? (acc[bi] + bv) : 0.f;
        a.out_pred[((size_t)b * TMz + tm1) * Vz + col] = r;
    }
}

__device__ void gwh_task(const KArgs& a, float* sm, int tk, int t) {
    int tid = threadIdx.x;
    int g = tk / 24, r = tk % 24, ct = r / 6, ks = r % 6;
    const float* Wg = (g == 0) ? a.W_i : (g == 1) ? a.W_f : (g == 2) ? a.W_o : (g == 3) ? a.W_g1 : a.W_g2;
    int col = ct * 64 + (tid & 63), bg = tid >> 6;
    float* xb = sm + 8704;
    int wbase, hoff = 0;
    if (ks < 4) {
        wbase = ks * 128;
        for (int idx = tid; idx < 1024; idx += 256) {
            int b = idx >> 5, kq = idx & 31;
            int cap = a.caps[a.ord[b] * Tz + t];
            float4 v = *(const float4*)&a.emb[(size_t)cap * 512 + ks * 128 + kq * 4];
            *(float4*)&xb[b * 128 + kq * 4] = v;
        }
        __syncthreads();
    } else {
        wbase = 768 + (ks - 4) * 128;
        hoff = (ks - 4) * 128;
    }
    float acc[8] = {0.f, 0.f, 0.f, 0.f, 0.f, 0.f, 0.f, 0.f};
    for (int kq = 0; kq < 32; ++kq) {
        float w0 = Wg[(size_t)(wbase + kq * 4 + 0) * 256 + col];
        float w1 = Wg[(size_t)(wbase + kq * 4 + 1) * 256 + col];
        float w2 = Wg[(size_t)(wbase + kq * 4 + 2) * 256 + col];
        float w3 = Wg[(size_t)(wbase + kq * 4 + 3) * 256 + col];
#pragma unroll
        for (int bi = 0; bi < 8; ++bi) {
            int b = bg * 8 + bi;
            const float* xr = (ks < 4) ? &xb[b * 128] : &sm[b * 256 + hoff];
            float4 x4 = *(const float4*)&xr[kq * 4];
            acc[bi] += x4.x * w0 + x4.y * w1 + x4.z * w2 + x4.w * w3;
        }
    }
#pragma unroll
    for (int bi = 0; bi < 8; ++bi)
        a.gwh[((size_t)((g * 6 + ks) * 32 + bg * 8 + bi)) * 256 + col] = acc[bi];
}

__global__ __launch_bounds__(256, 2) void k_steps(KArgs a) {
    __shared__ __align__(16) float sm[12800];
    int bid = blockIdx.x, tid = threadIdx.x;
    int b = bid >> 4, sub = bid & 15;
    int gen = 0;

    for (int t = 0; t < TMz; ++t) {
        // ---------- Phase A: at2, e, expe, zpart, awfp (+pred(t-1), +gwh) ----------
        bool fullh = (bid < 157) || (bid >= 392);
        if (fullh) {
            for (int i = tid; i < 2048; i += 256) ((float4*)sm)[i] = ((const float4*)a.hst)[i];
        } else {
            if (tid < 64) ((float4*)sm)[b * 64 + tid] = ((const float4*)a.hst)[b * 64 + tid];
        }
        __syncthreads();
        int ordb = a.ord[b];
        {
            float v = a.b_dec[tid];
            const float* hb = sm + b * 256;
            for (int k = 0; k < 256; k += 4) {
                float4 h4 = *(const float4*)&hb[k];
                v += h4.x * a.W_dec[(k + 0) * 256 + tid] + h4.y * a.W_dec[(k + 1) * 256 + tid]
                   + h4.z * a.W_dec[(k + 2) * 256 + tid] + h4.w * a.W_dec[(k + 3) * 256 + tid];
            }
            sm[8192 + tid] = v;
        }
        __syncthreads();
        {
            int wv = tid >> 6, ln = tid & 63;
            float4 wf4 = *(const float4*)&a.W_full[ln * 4];
            float4 a24 = *(const float4*)&sm[8192 + ln * 4];
            float bf = a.b_full[0];
            float zac = 0.f;
            for (int i = 0; i < 16; ++i) {
                int p = sub * 64 + wv * 16 + i;
                float4 r4 = *(const float4*)&a.att1[((size_t)(b * 1024 + p)) * 256 + ln * 4];
                float s = fmaxf(r4.x + a24.x, 0.f) * wf4.x + fmaxf(r4.y + a24.y, 0.f) * wf4.y
                        + fmaxf(r4.z + a24.z, 0.f) * wf4.z + fmaxf(r4.w + a24.w, 0.f) * wf4.w;
                s += __shfl_down(s, 32); s += __shfl_down(s, 16); s += __shfl_down(s, 8);
                s += __shfl_down(s, 4);  s += __shfl_down(s, 2);  s += __shfl_down(s, 1);
                if (ln == 0) {
                    float ex = expf(s + bf);
                    a.expe[b * 1024 + p] = ex;
                    sm[8448 + wv * 16 + i] = ex;
                    zac += ex;
                }
            }
            if (ln == 0) sm[8576 + wv] = zac;
        }
        __syncthreads();
        if (tid == 0) a.zpart[b * 16 + sub] = sm[8576] + sm[8577] + sm[8578] + sm[8579];
        {
            const float* ib = a.info + (size_t)ordb * INFLAT + (size_t)(sub * 64) * 256;
            float q0 = 0.f, q1 = 0.f, q2 = 0.f, q3 = 0.f;
            for (int i = 0; i < 64; i += 4) {
                q0 += sm[8448 + i + 0] * ib[(size_t)(i + 0) * 256 + tid];
                q1 += sm[8448 + i + 1] * ib[(size_t)(i + 1) * 256 + tid];
                q2 += sm[8448 + i + 2] * ib[(size_t)(i + 2) * 256 + tid];
                q3 += sm[8448 + i + 3] * ib[(size_t)(i + 3) * 256 + tid];
            }
            a.awfp[((size_t)(b * 16 + sub)) * 256 + tid] = (q0 + q1) + (q2 + q3);
        }
        if (t > 0 && bid < 157) pred_task(a, sm, bid, t - 1);
        if (bid >= 392) gwh_task(a, sm, bid - 392, t);
        gbar(a.slots, a.root, ++gen);

        // ---------- Phase B: gate pre-activations (160 blocks) ----------
        if (sub < 5) {
            int g = sub;
            const float* Wg = (g == 0) ? a.W_i : (g == 1) ? a.W_f : (g == 2) ? a.W_o : (g == 3) ? a.W_g1 : a.W_g2;
            const float* bg = (g == 0) ? a.b_i : (g == 1) ? a.b_f : (g == 2) ? a.b_o : (g == 3) ? a.b_g1 : a.b_g2;
            float Z = 0.f;
#pragma unroll
            for (int c = 0; c < 16; ++c) Z += a.zpart[b * 16 + c];
            float invZ = 1.0f / Z;
            float aw = 0.f;
#pragma unroll
            for (int c = 0; c < 16; ++c) aw += a.awfp[((size_t)(b * 16 + c)) * 256 + tid];
            sm[tid] = aw * invZ;
            __syncthreads();
            float s = bg[tid];
#pragma unroll
            for (int ks = 0; ks < 6; ++ks) s += a.gwh[((size_t)((g * 6 + ks) * 32 + b)) * 256 + tid];
            float s0 = 0.f, s1 = 0.f, s2 = 0.f, s3 = 0.f;
            for (int kq = 0; kq < 64; ++kq) {
                float4 x4 = *(const float4*)&sm[kq * 4];
                s0 += x4.x * Wg[(size_t)(512 + kq * 4 + 0) * 256 + tid];
                s1 += x4.y * Wg[(size_t)(512 + kq * 4 + 1) * 256 + tid];
                s2 += x4.z * Wg[(size_t)(512 + kq * 4 + 2) * 256 + tid];
                s3 += x4.w * Wg[(size_t)(512 + kq * 4 + 3) * 256 + tid];
            }
            a.gsg[((size_t)(g * 32 + b)) * 256 + tid] = s + (s0 + s1) + (s2 + s3);
        }
        gbar(a.slots, a.root, ++gen);

        // ---------- Phase C: cell + mlp + h + alpha (all 512 blocks) ----------
        {
            int j = tid;
            float Z = 0.f;
#pragma unroll
            for (int c = 0; c < 16; ++c) Z += a.zpart[b * 16 + c];
            float invZ = 1.0f / Z;
            float am = (a.slp[b] > t) ? invZ : 0.f;
            if (tid < 64) {
                int p = sub * 64 + tid;
                a.out_alpha[((size_t)b * TMz + t) * 1024 + p] = a.expe[b * 1024 + p] * am;
            }
            float giv = a.gsg[((size_t)(0 * 32 + b)) * 256 + j];
            float gfv = a.gsg[((size_t)(1 * 32 + b)) * 256 + j];
            float gov = a.gsg[((size_t)(2 * 32 + b)) * 256 + j];
            float gg1 = a.gsg[((size_t)(3 * 32 + b)) * 256 + j];
            float gg2 = a.gsg[((size_t)(4 * 32 + b)) * 256 + j];
            float iv = sigm(giv), fv = sigm(gfv), ov = sigm(gov);
            float g1 = tanhf(gg1), g2 = tanhf(gg2);
            float nc = fv * a.cst[b * 256 + j] + iv * g1;
            float nC = fv * a.Cst[b * 256 + j] + iv * g2;
            if (sub == 0) { a.cst[b * 256 + j] = nc; a.Cst[b * 256 + j] = nC; }
            sm[j] = nc;
            sm[256 + j] = nC;
            sm[512 + j] = ov;
            __syncthreads();
            // mlp slice: 16 cols, k split 16-way (32 each)
            int colL = tid & 15, kth = tid >> 4;
            int col = sub * 16 + colL;
            float part = 0.f;
            for (int i = 0; i < 32; ++i) {
                int k = kth * 32 + i;
                part += sm[k] * a.W_mlp[(size_t)k * 256 + col];
            }
            sm[768 + colL * 17 + kth] = part;
            __syncthreads();
            if (tid < 16) {
                int c2 = sub * 16 + tid;
                float m = a.b_mlp[c2];
#pragma unroll
                for (int kk = 0; kk < 16; ++kk) m += sm[768 + tid * 17 + kk];
                a.hst[b * 256 + c2] = sm[512 + c2] * tanhf(m);
            }
        }
        gbar(a.slots, a.root, ++gen);
    }

    // epilogue: pred for t = 18
    for (int i = tid; i < 2048; i += 256) ((float4*)sm)[i] = ((const float4*)a.hst)[i];
    __syncthreads();
    if (bid < 157) pred_task(a, sm, bid, TMz - 1);
}

extern "C" void kernel_launch(void* const* d_in, const int* in_sizes, int n_in,
                              void* d_out, int out_size, void* d_ws, size_t ws_size,
                              hipStream_t stream) {
    const float* info  = (const float*)d_in[0];
    const float* rel   = (const float*)d_in[1];
    const int*   caps  = (const int*)d_in[2];
    const int*   lens  = (const int*)d_in[3];
    const float* emb   = (const float*)d_in[4];
    const float* W_enc = (const float*)d_in[5];
    const float* b_enc = (const float*)d_in[6];
    const float* W_dec = (const float*)d_in[7];
    const float* b_dec = (const float*)d_in[8];
    const float* W_full= (const float*)d_in[9];
    const float* b_full= (const float*)d_in[10];
    const float* W_i   = (const float*)d_in[11];
    const float* b_i   = (const float*)d_in[12];
    const float* W_f   = (const float*)d_in[13];
    const float* b_f   = (const float*)d_in[14];
    const float* W_o   = (const float*)d_in[15];
    const float* b_o   = (const float*)d_in[16];
    const float* W_g1  = (const float*)d_in[17];
    const float* b_g1  = (const float*)d_in[18];
    const float* W_g2  = (const float*)d_in[19];
    const float* b_g2  = (const float*)d_in[20];
    const float* W_mlp = (const float*)d_in[21];
    const float* b_mlp = (const float*)d_in[22];
    const float* W_fc  = (const float*)d_in[25];
    const float* b_fc  = (const float*)d_in[26];
    const float* W_ih  = (const float*)d_in[27];
    const float* b_ih  = (const float*)d_in[28];
    const float* W_ic  = (const float*)d_in[29];
    const float* b_ic  = (const float*)d_in[30];
    const float* W_iC  = (const float*)d_in[31];
    const float* b_iC  = (const float*)d_in[32];

    float* out = (float*)d_out;
    float* out_pred  = out;
    float* out_alpha = out + (size_t)Bz * TMz * Vz;
    float* out_order = out_alpha + (size_t)Bz * TMz * 1024;

    float* w = (float*)d_ws;
    float* ph   = w + WS_PH;
    float* pcp  = w + WS_PC;
    float* att1 = w + WS_ATT1;
    float* expe = w + WS_EXPE;
    float* zpart= w + WS_ZPART;
    float* awfp = w + WS_AWFP;
    float* gwh  = w + WS_GWH;
    float* gsg  = w + WS_GSG;
    float* hst  = w + WS_HST;
    float* cst  = w + WS_CST;
    float* Cst  = w + WS_CSTB;
    int*   ordp = (int*)(w + WS_INTS);
    int*   slp  = ordp + 32;
    int*   barmem = ordp + 64;          // root@0, slots@64..575
    float* pC   = w + WS_PCHC;

    k_sort<<<1, 64, 0, stream>>>(lens, out_order, ordp, slp, barmem);
    k_gemv2<<<512, 256, 0, stream>>>(info, ordp, W_ih, W_ic, ph, pcp);
    k_gemvC<<<128, 256, 0, stream>>>(rel, ordp, W_iC, pC);
    k_reduce3<<<96, 256, 0, stream>>>(ph, pcp, pC, b_ih, b_ic, b_iC, hst, cst, Cst);
    k_att1<<<1024, 256, 0, stream>>>(info, ordp, W_enc, b_enc, att1);

    KArgs ka;
    ka.info = info; ka.emb = emb; ka.W_dec = W_dec; ka.b_dec = b_dec;
    ka.W_full = W_full; ka.b_full = b_full;
    ka.W_i = W_i; ka.W_f = W_f; ka.W_o = W_o; ka.W_g1 = W_g1; ka.W_g2 = W_g2;
    ka.b_i = b_i; ka.b_f = b_f; ka.b_o = b_o; ka.b_g1 = b_g1; ka.b_g2 = b_g2;
    ka.W_mlp = W_mlp; ka.b_mlp = b_mlp; ka.W_fc = W_fc; ka.b_fc = b_fc;
    ka.caps = caps;
    ka.att1 = att1; ka.expe = expe; ka.zpart = zpart; ka.awfp = awfp; ka.gwh = gwh;
    ka.gsg = gsg; ka.hst = hst; ka.cst = cst; ka.Cst = Cst;
    ka.ord = ordp; ka.slp = slp;
    ka.root = barmem; ka.slots = barmem + 64;
    ka.out_pred = out_pred; ka.out_alpha = out_alpha;

    k_steps<<<NBLK, 256, 0, stream>>>(ka);
}